// Round 6
// baseline (137.162 us; speedup 1.0000x reference)
//
#include <hip/hip_runtime.h>

#define NSPEC  3
#define EMBEDD 16
#define KMAX   32
#define RCUT   5.0f

// triu_indices(8) row-major
__constant__ int TUN[36] = {0,0,0,0,0,0,0,0, 1,1,1,1,1,1,1, 2,2,2,2,2,2, 3,3,3,3,3, 4,4,4,4, 5,5,5, 6,6, 7};
__constant__ int TUM[36] = {0,1,2,3,4,5,6,7, 1,2,3,4,5,6,7, 2,3,4,5,6,7, 3,4,5,6,7, 4,5,6,7, 5,6,7, 6,7, 7};

// ws layout:
//   [0..79]    wstruct[16+t]/sscale[t]
//   [80..330]  wmag[16+t]/mscale[t]
//   [331]      bstruct+bmag - sum_t w*shift/scale
//   [332..347] wstruct[l]+wmag[l]
//   [400..463] cw1T[m*8+n] (transposed dmi weights /scale)
//   [464..527] cw2T[m*8+n] (transposed u*dmi weights /scale)
//   [1024 .. 1024+ 8E)  phi8[e][8]   (written by edges kernel)
//   [.. +4E)            r4[e] = (rhx, rhy, rhz, dist)
//   [.. +4E)            md4[e] = (mdx, mdy, mdz, uj)

// ---- DPP helpers ----
template<int CTRL, int RMASK, bool BC>
__device__ __forceinline__ float dpp_mov0(float x) {
    return __int_as_float(__builtin_amdgcn_update_dpp(
        0, __float_as_int(x), CTRL, RMASK, 0xF, BC));
}
__device__ __forceinline__ float prefix32(float x) {
    x += dpp_mov0<0x111, 0xF, true >(x);   // row_shr:1
    x += dpp_mov0<0x112, 0xF, true >(x);   // row_shr:2
    x += dpp_mov0<0x114, 0xF, true >(x);   // row_shr:4
    x += dpp_mov0<0x118, 0xF, true >(x);   // row_shr:8
    x += dpp_mov0<0x142, 0xA, false>(x);   // row_bcast15 -> rows 1,3
    return x;
}
__device__ __forceinline__ float swz_xor16(float x) {
    return __int_as_float(__builtin_amdgcn_ds_swizzle(__float_as_int(x), 0x401F));
}
__device__ __forceinline__ float red_k4(float x) {
    x += dpp_mov0<0x128, 0xF, true>(x);    // row_ror:8 == xor 8
    x += swz_xor16(x);                     // xor 16
    return x;
}
__device__ __forceinline__ float red32(float x) {
    x += dpp_mov0<0x121, 0xF, true>(x);
    x += dpp_mov0<0x122, 0xF, true>(x);
    x += dpp_mov0<0x124, 0xF, true>(x);
    x += dpp_mov0<0x128, 0xF, true>(x);
    x += swz_xor16(x);
    return x;
}
__device__ __forceinline__ void lds_fence() {
    asm volatile("s_waitcnt lgkmcnt(0)" ::: "memory");
}

// ---- setup (runs as the extra block of magpot_edges) ----
__device__ void do_setup(const float* sshift, const float* sscale,
                         const float* mshift, const float* mscale,
                         const float* wstruct, const float* bstruct,
                         const float* wmag, const float* bmag,
                         float* ws)
{
    __shared__ float red[4];
    const int t = threadIdx.x;
    float c = 0.0f;
    for (int idx = t; idx < 80; idx += 256) {
        const float w = wstruct[16 + idx] / sscale[idx];
        ws[idx] = w;
        c += w * sshift[idx];
    }
    for (int idx = t; idx < 251; idx += 256) {
        const float w = wmag[16 + idx] / mscale[idx];
        ws[80 + idx] = w;
        c += w * mshift[idx];
    }
    if (t < EMBEDD) ws[332 + t] = wstruct[t] + wmag[t];
    if (t < 64) {   // transposed DMI weight tables (t = n*8+m)
        const int n = t >> 3, m = t & 7;
        ws[400 + m*8 + n] = wmag[16 + 83 + t]  / mscale[83 + t];
        ws[464 + m*8 + n] = wmag[16 + 163 + t] / mscale[163 + t];
    }
    #pragma unroll
    for (int d = 1; d <= 32; d <<= 1) c += __shfl_xor(c, d, 64);
    if ((t & 63) == 0) red[t >> 6] = c;
    __syncthreads();
    if (t == 0) ws[331] = bstruct[0] + bmag[0] - (red[0] + red[1] + red[2] + red[3]);
}

// ---- per-edge prologue: all gathers + chebyshev + phi, coalesced writes ----
__global__ __launch_bounds__(256)
void magpot_edges(const float* __restrict__ pos,
                  const int*   __restrict__ species,
                  const float* __restrict__ mag,
                  const int*   __restrict__ eidx,
                  const float* __restrict__ shifts,
                  const float* __restrict__ rb,
                  const float* __restrict__ sshift, const float* __restrict__ sscale,
                  const float* __restrict__ mshift, const float* __restrict__ mscale,
                  const float* __restrict__ wstruct, const float* __restrict__ bstruct,
                  const float* __restrict__ wmag, const float* __restrict__ bmag,
                  float* __restrict__ ws,
                  int E, int nEdgeBlocks)
{
    if ((int)blockIdx.x == nEdgeBlocks) {   // appended setup block
        do_setup(sshift, sscale, mshift, mscale, wstruct, bstruct, wmag, bmag, ws);
        return;
    }
    const int e = blockIdx.x * 256 + threadIdx.x;
    if (e >= E) return;

    const int i = eidx[e];        // i_idx
    const int j = eidx[E + e];    // j_idx
    const float rx = pos[3*j+0] - pos[3*i+0] + shifts[3*e+0];
    const float ry = pos[3*j+1] - pos[3*i+1] + shifts[3*e+1];
    const float rz = pos[3*j+2] - pos[3*i+2] + shifts[3*e+2];
    const float dist = sqrtf(rx*rx + ry*ry + rz*rz);
    const float fc = (dist < RCUT)
        ? (0.5f * __builtin_amdgcn_cosf(dist * 0.1f) + 0.5f)   // cos(pi d/5), revolutions
        : 0.0f;
    const float xr = dist * (1.0f/RCUT);
    const float x  = 2.0f * xr * xr - 1.0f;
    float f[8];
    {
        float Tm2 = 1.0f, Tm1 = x;
        f[0] = 0.5f * (Tm2 + 1.0f) * fc;
        f[1] = 0.5f * (Tm1 + 1.0f) * fc;
        #pragma unroll
        for (int k = 2; k < 8; ++k) {
            const float T = 2.0f * x * Tm1 - Tm2;
            Tm2 = Tm1; Tm1 = T;
            f[k] = 0.5f * (T + 1.0f) * fc;
        }
    }
    const int pair = species[i] * NSPEC + species[j];
    const float4* rb4 = (const float4*)(rb + pair * 64);
    float4 ph0, ph1;
    {
        float phv[8];
        #pragma unroll
        for (int n = 0; n < 8; ++n) {
            const float4 r0 = rb4[n*2+0];
            const float4 r1 = rb4[n*2+1];
            phv[n] = r0.x*f[0] + r0.y*f[1] + r0.z*f[2] + r0.w*f[3]
                   + r1.x*f[4] + r1.y*f[5] + r1.z*f[6] + r1.w*f[7];
        }
        ph0 = make_float4(phv[0], phv[1], phv[2], phv[3]);
        ph1 = make_float4(phv[4], phv[5], phv[6], phv[7]);
    }
    const float dinv = 1.0f / fmaxf(dist, 1e-8f);
    const float mjx = mag[3*j+0], mjy = mag[3*j+1], mjz = mag[3*j+2];
    const float uj = mjx*mjx + mjy*mjy + mjz*mjz;
    const float mnj = sqrtf(uj);
    const float mjinv = (mnj > 1e-8f) ? (1.0f / mnj) : 0.0f;

    float4* phi8 = (float4*)(ws + 1024);
    float4* r4g  = (float4*)(ws + 1024 + 8*(size_t)E);
    float4* md4g = (float4*)(ws + 1024 + 12*(size_t)E);
    phi8[2*e]   = ph0;
    phi8[2*e+1] = ph1;
    r4g[e]  = make_float4(rx*dinv, ry*dinv, rz*dinv, dist);
    md4g[e] = make_float4(mjx*mjinv, mjy*mjinv, mjz*mjinv, uj);
}

struct __align__(16) AtomLds {
    float P4[32];    // P rows padded to float4
    float Q8[64];    // Q rows padded to 8 (xx,xy,xz,yy,yz,zz,0,0)
    float M4[32];
    float mQ4[32];
    float wv4[32];   // m_i x M[m]
};  // 192 floats = 768 B

__global__ __launch_bounds__(256)
void magpot_main(const int*   __restrict__ species,
                 const float* __restrict__ mag,
                 const float* __restrict__ semb,
                 const float* __restrict__ aes,
                 const float* __restrict__ ws,
                 float* __restrict__ out,
                 int N, int E, int K)
{
    __shared__ AtomLds lds[8];

    const int lane64 = threadIdx.x & 63;
    const int wv     = threadIdx.x >> 6;
    const int h      = lane64 >> 5;
    const int s      = lane64 & 31;
    const int ea     = 31 - s;             // edge index (reversed: suffix -> DPP prefix)
    const int i      = blockIdx.x * 8 + wv * 2 + h;
    const bool valid = (i < N);
    const int isafe  = valid ? i : 0;
    AtomLds& L = lds[wv * 2 + h];

    const float* wm = ws + 80;
    const float*  phig  = ws + 1024;                          // phi[e*8+n]
    const float4* phi8g = (const float4*)(ws + 1024);
    const float4* r4g   = (const float4*)(ws + 1024 + 8*(size_t)E);
    const float4* md4g  = (const float4*)(ws + 1024 + 12*(size_t)E);

    // ---- atom-level ----
    const int   spi = species[isafe];
    const float mgx = mag[3*isafe+0], mgy = mag[3*isafe+1], mgz = mag[3*isafe+2];
    const float u_i = mgx*mgx + mgy*mgy + mgz*mgz;
    const float mn_i = sqrtf(u_i);
    const float mi_inv = (mn_i > 1e-8f) ? (1.0f / mn_i) : 0.0f;
    const float mix = mgx*mi_inv, miy = mgy*mi_inv, miz = mgz*mi_inv;

    // ---- phase 1: streaming per-edge loads (no gathers, no chains) ----
    float phi[8];
    float rx = 0.0f, ry = 0.0f, rz = 0.0f;
    #pragma unroll
    for (int n = 0; n < 8; ++n) phi[n] = 0.0f;
    if (ea < K) {
        const int e = isafe * K + ea;
        const float4 p0 = phi8g[2*e], p1 = phi8g[2*e+1];
        phi[0]=p0.x; phi[1]=p0.y; phi[2]=p0.z; phi[3]=p0.w;
        phi[4]=p1.x; phi[5]=p1.y; phi[6]=p1.z; phi[7]=p1.w;
        const float4 rv = r4g[e];
        rx = rv.x * rv.w; ry = rv.y * rv.w; rz = rv.z * rv.w;   // r = rhat*dist
    }

    float p = 0.0f;

    // ---- phase 2: segment sums from L1-hot global (k-group broadcast reads) ----
    {
        const int k4 = s >> 3;
        const int n  = s & 7;
        const int base = isafe * K + k4*8;

        float a_dr = 0.0f;
        float aP0 = 0.0f, aP1 = 0.0f, aP2 = 0.0f;
        float aQ0 = 0.0f, aQ1 = 0.0f, aQ2 = 0.0f, aQ3 = 0.0f, aQ4 = 0.0f, aQ5 = 0.0f;
        float aM0 = 0.0f, aM1 = 0.0f, aM2 = 0.0f;
        float a_nb = 0.0f;
        float aW0 = 0.0f, aW1 = 0.0f, aW2 = 0.0f;

        #pragma unroll
        for (int q = 0; q < 8; ++q) {
            const bool ok = (k4*8 + q) < K;
            const int ee = ok ? (base + q) : (isafe * K);
            float ph = phig[(size_t)ee*8 + n];
            ph = ok ? ph : 0.0f;
            const float4 rv = r4g[ee];
            const float4 mv = md4g[ee];
            const float hx = rv.x, hy = rv.y, hz = rv.z;
            a_dr += ph;
            aP0 += ph*hx; aP1 += ph*hy; aP2 += ph*hz;
            aQ0 += ph*(hx*hx - (1.0f/3.0f));
            aQ1 += ph*(hx*hy);
            aQ2 += ph*(hx*hz);
            aQ3 += ph*(hy*hy - (1.0f/3.0f));
            aQ4 += ph*(hy*hz);
            aQ5 += ph*(hz*hz - (1.0f/3.0f));
            aM0 += ph*mv.x; aM1 += ph*mv.y; aM2 += ph*mv.z;
            const float pu = ph*mv.w;
            a_nb += pu;
            aW0 += pu*mv.x; aW1 += pu*mv.y; aW2 += pu*mv.z;
        }
        a_dr = red_k4(a_dr);
        aP0 = red_k4(aP0); aP1 = red_k4(aP1); aP2 = red_k4(aP2);
        aQ0 = red_k4(aQ0); aQ1 = red_k4(aQ1); aQ2 = red_k4(aQ2);
        aQ3 = red_k4(aQ3); aQ4 = red_k4(aQ4); aQ5 = red_k4(aQ5);
        aM0 = red_k4(aM0); aM1 = red_k4(aM1); aM2 = red_k4(aM2);
        a_nb = red_k4(a_nb);
        aW0 = red_k4(aW0); aW1 = red_k4(aW1); aW2 = red_k4(aW2);

        if (k4 == 0) {
            ((float4*)L.P4)[n]     = make_float4(aP0, aP1, aP2, 0.0f);
            ((float4*)L.Q8)[2*n]   = make_float4(aQ0, aQ1, aQ2, aQ3);
            ((float4*)L.Q8)[2*n+1] = make_float4(aQ4, aQ5, 0.0f, 0.0f);
            ((float4*)L.M4)[n]     = make_float4(aM0, aM1, aM2, 0.0f);
            const float mq0 = aQ0*mix + aQ1*miy + aQ2*miz;
            const float mq1 = aQ1*mix + aQ3*miy + aQ4*miz;
            const float mq2 = aQ2*mix + aQ4*miy + aQ5*miz;
            ((float4*)L.mQ4)[n]    = make_float4(mq0, mq1, mq2, 0.0f);
            ((float4*)L.wv4)[n]    = make_float4(miy*aM2 - miz*aM1,
                                                 miz*aM0 - mix*aM2,
                                                 mix*aM1 - miy*aM0, 0.0f);
            // folded per-n descriptors (diso/dsia/dnex + radial + nbr_amp)
            const float diso = mix*aM0 + miy*aM1 + miz*aM2;
            const float dsia = aQ0*mix*mix + aQ3*miy*miy + aQ5*miz*miz
                             + 2.0f*(aQ1*mix*miy + aQ2*mix*miz + aQ4*miy*miz);
            const float dnex = mix*aW0 + miy*aW1 + miz*aW2;
            p += a_dr * ws[n] + a_nb * wm[227 + n]
               + diso * wm[3 + n]  + dsia * wm[11 + n]  + dnex * wm[235 + n]
               + u_i * (diso * wm[147 + n] + dsia * wm[155 + n] + dnex * wm[243 + n]);
        }
        if (s == 8) {
            const float u2 = u_i * u_i;
            p += u_i * wm[0] + u2 * wm[1] + u2 * u_i * wm[2];
        }
        if (s < EMBEDD)
            p += semb[spi * EMBEDD + s] * ws[332 + s];
    }
    lds_fence();   // phase-2 LDS stores -> phase-3/4 reads (intra-wave)

    // ---- phase 3: DMI, fused weights (no d_dmi materialization) ----
    {
        float B[8];
        #pragma unroll
        for (int m = 0; m < 8; ++m) {
            float a1 = 0.0f, a2 = 0.0f;
            #pragma unroll
            for (int n = 0; n < 8; ++n) {
                a1 = fmaf(phi[n], ws[400 + m*8 + n], a1);
                a2 = fmaf(phi[n], ws[464 + m*8 + n], a2);
            }
            B[m] = a1 + u_i * a2;
        }
        float cdmi = 0.0f;
        #pragma unroll
        for (int m = 0; m < 8; ++m) {
            const float4 wvm = ((const float4*)L.wv4)[m];
            const float vx = phi[m] * rx;
            const float vy = phi[m] * ry;
            const float vz = phi[m] * rz;
            const float Sx = prefix32(vx) - vx;   // exclusive suffix (b > ea)
            const float Sy = prefix32(vy) - vy;
            const float Sz = prefix32(vz) - vz;
            const float cx = ry*Sz - rz*Sy;
            const float cy = rz*Sx - rx*Sz;
            const float cz = rx*Sy - ry*Sx;
            cdmi = fmaf(B[m], cx*wvm.x + cy*wvm.y + cz*wvm.z, cdmi);
        }
        p += cdmi;
    }

    // ---- phase 4b: d_sae + PP/QQ upper triangles ----
    {
        #pragma unroll
        for (int t2 = 0; t2 < 2; ++t2) {
            const int idx = s + t2*32;
            const int m4 = idx >> 3, n4 = idx & 7;
            const float4 mQm = ((const float4*)L.mQ4)[m4];
            const float4 Mn  = ((const float4*)L.M4)[n4];
            p += (mQm.x*Mn.x + mQm.y*Mn.y + mQm.z*Mn.z) * wm[19 + idx];
        }
        #pragma unroll
        for (int t2 = 0; t2 < 2; ++t2) {
            const int idx = s + t2*32;
            if (idx < 36) {
                const int a = TUN[idx], b = TUM[idx];
                const float4 Pa = ((const float4*)L.P4)[a];
                const float4 Pb = ((const float4*)L.P4)[b];
                const float pp = Pa.x*Pb.x + Pa.y*Pb.y + Pa.z*Pb.z;
                const float4 Qa0 = ((const float4*)L.Q8)[2*a], Qa1 = ((const float4*)L.Q8)[2*a+1];
                const float4 Qb0 = ((const float4*)L.Q8)[2*b], Qb1 = ((const float4*)L.Q8)[2*b+1];
                const float qq = Qa0.x*Qb0.x + Qa0.w*Qb0.w + Qa1.y*Qb1.y
                       + 2.0f*(Qa0.y*Qb0.y + Qa0.z*Qb0.z + Qa1.x*Qb1.x);
                p += pp * ws[8 + idx] + qq * ws[44 + idx];
            }
        }
    }

    p = red32(p);
    if (s == 0 && valid)
        out[i] = p + ws[331] + aes[spi];
}

extern "C" void kernel_launch(void* const* d_in, const int* in_sizes, int n_in,
                              void* d_out, int out_size, void* d_ws, size_t ws_size,
                              hipStream_t stream) {
    const float* pos     = (const float*)d_in[0];
    const int*   spc     = (const int*)  d_in[1];
    const float* mg      = (const float*)d_in[2];
    const int*   eidx    = (const int*)  d_in[3];
    const float* shf     = (const float*)d_in[4];
    const float* rb      = (const float*)d_in[5];
    const float* semb    = (const float*)d_in[6];
    const float* sshift  = (const float*)d_in[7];
    const float* sscale  = (const float*)d_in[8];
    const float* mshift  = (const float*)d_in[9];
    const float* mscale  = (const float*)d_in[10];
    const float* aes     = (const float*)d_in[11];
    const float* wstruct = (const float*)d_in[12];
    const float* bstruct = (const float*)d_in[13];
    const float* wmag    = (const float*)d_in[14];
    const float* bmag    = (const float*)d_in[15];
    float* out = (float*)d_out;
    float* ws  = (float*)d_ws;

    const int N = in_sizes[1];
    const int E = in_sizes[3] / 2;
    const int K = E / N;

    const int nEdgeBlocks = (E + 255) / 256;
    hipLaunchKernelGGL(magpot_edges, dim3(nEdgeBlocks + 1), dim3(256), 0, stream,
                       pos, spc, mg, eidx, shf, rb,
                       sshift, sscale, mshift, mscale, wstruct, bstruct, wmag, bmag,
                       ws, E, nEdgeBlocks);
    hipLaunchKernelGGL(magpot_main, dim3((N + 7) / 8), dim3(256), 0, stream,
                       spc, mg, semb, aes, ws, out, N, E, K);
}

// Round 7
// 119.682 us; speedup vs baseline: 1.1461x; 1.1461x over previous
//
#include <hip/hip_runtime.h>

#define NSPEC  3
#define EMBEDD 16
#define KMAX   32
#define RCUT   5.0f
#define PADR   36   // padded row stride (floats) for phiT

typedef float v2f __attribute__((ext_vector_type(2)));

// triu_indices(8) row-major
__constant__ int TUN[36] = {0,0,0,0,0,0,0,0, 1,1,1,1,1,1,1, 2,2,2,2,2,2, 3,3,3,3,3, 4,4,4,4, 5,5,5, 6,6, 7};
__constant__ int TUM[36] = {0,1,2,3,4,5,6,7, 1,2,3,4,5,6,7, 2,3,4,5,6,7, 3,4,5,6,7, 4,5,6,7, 5,6,7, 6,7, 7};

// ws layout (from magpot_setup):
//   [0..79]    wstruct[16+t]/sscale[t]
//   [80..330]  wmag[16+t]/mscale[t]
//   [331]      bstruct+bmag - sum_t w*shift/scale
//   [332..347] wstruct[l]+wmag[l]
//   [400..463] cw1[n*8+m] = wmag[16+83+n*8+m]/mscale[83+n*8+m]    (row-major: m-pairs adjacent)
//   [464..527] cw2[n*8+m] = wmag[16+163+n*8+m]/mscale[163+n*8+m]

// ---- DPP helpers ----
template<int CTRL, int RMASK, bool BC>
__device__ __forceinline__ float dpp_mov0(float x) {
    return __int_as_float(__builtin_amdgcn_update_dpp(
        0, __float_as_int(x), CTRL, RMASK, 0xF, BC));
}
__device__ __forceinline__ float prefix32(float x) {
    x += dpp_mov0<0x111, 0xF, true >(x);   // row_shr:1
    x += dpp_mov0<0x112, 0xF, true >(x);   // row_shr:2
    x += dpp_mov0<0x114, 0xF, true >(x);   // row_shr:4
    x += dpp_mov0<0x118, 0xF, true >(x);   // row_shr:8
    x += dpp_mov0<0x142, 0xA, false>(x);   // row_bcast15 -> rows 1,3
    return x;
}
__device__ __forceinline__ float swz_xor16(float x) {
    return __int_as_float(__builtin_amdgcn_ds_swizzle(__float_as_int(x), 0x401F));
}
__device__ __forceinline__ float red_k4(float x) {   // reduce lane bits 3,4
    x += dpp_mov0<0x128, 0xF, true>(x);    // row_ror:8 == xor 8
    x += swz_xor16(x);                     // xor 16 (within each 32-half)
    return x;
}
__device__ __forceinline__ v2f red_k4_v2(v2f v) {
    v2f t;
    t.x = dpp_mov0<0x128, 0xF, true>(v.x);
    t.y = dpp_mov0<0x128, 0xF, true>(v.y);
    v += t;
    t.x = swz_xor16(v.x);
    t.y = swz_xor16(v.y);
    v += t;
    return v;
}
__device__ __forceinline__ float red32(float x) {    // full 32-half sum
    x += dpp_mov0<0x121, 0xF, true>(x);
    x += dpp_mov0<0x122, 0xF, true>(x);
    x += dpp_mov0<0x124, 0xF, true>(x);
    x += dpp_mov0<0x128, 0xF, true>(x);
    x += swz_xor16(x);
    return x;
}
__device__ __forceinline__ void lds_fence() {
    asm volatile("s_waitcnt lgkmcnt(0)" ::: "memory");
}

struct __align__(16) AtomLds {
    float phiT[8 * PADR];                     // 288: phiT[n*PADR + a]
    float rhx[KMAX], rhy[KMAX], rhz[KMAX];    // edge data (phase 1 -> 2 only)
    float mdx[KMAX], mdy[KMAX], mdz[KMAX];
    float uj[KMAX];
    float P4[8*4];    // P rows padded to float4
    float Q8[8*8];    // Q rows padded to 8 (xx,xy,xz,yy,yz,zz,0,0)
    float M4[8*4];
    float mQ4[8*4];
    float wv4[8*4];   // m_i x M[m], padded
};

__global__ __launch_bounds__(256)
void magpot_setup(const float* __restrict__ sshift, const float* __restrict__ sscale,
                  const float* __restrict__ mshift, const float* __restrict__ mscale,
                  const float* __restrict__ wstruct, const float* __restrict__ bstruct,
                  const float* __restrict__ wmag, const float* __restrict__ bmag,
                  float* __restrict__ ws)
{
    __shared__ float red[4];
    const int t = threadIdx.x;
    float c = 0.0f;
    for (int idx = t; idx < 80; idx += 256) {
        const float w = wstruct[16 + idx] / sscale[idx];
        ws[idx] = w;
        c += w * sshift[idx];
    }
    for (int idx = t; idx < 251; idx += 256) {
        const float w = wmag[16 + idx] / mscale[idx];
        ws[80 + idx] = w;
        c += w * mshift[idx];
    }
    if (t < EMBEDD) ws[332 + t] = wstruct[t] + wmag[t];
    if (t < 64) {   // DMI weight tables, row-major [n][m] (m-pairs adjacent)
        ws[400 + t] = wmag[16 + 83 + t]  / mscale[83 + t];
        ws[464 + t] = wmag[16 + 163 + t] / mscale[163 + t];
    }
    #pragma unroll
    for (int d = 1; d <= 32; d <<= 1) c += __shfl_xor(c, d, 64);
    if ((t & 63) == 0) red[t >> 6] = c;
    __syncthreads();
    if (t == 0) ws[331] = bstruct[0] + bmag[0] - (red[0] + red[1] + red[2] + red[3]);
}

__global__ __launch_bounds__(256)
void magpot_main(const float* __restrict__ pos,
                 const int*   __restrict__ species,
                 const float* __restrict__ mag,
                 const int*   __restrict__ eidx,
                 const float* __restrict__ shifts,
                 const float* __restrict__ rb,
                 const float* __restrict__ semb,
                 const float* __restrict__ aes,
                 const float* __restrict__ ws,
                 float* __restrict__ out,
                 int N, int E, int K)
{
    __shared__ AtomLds lds[8];

    const int lane64 = threadIdx.x & 63;
    const int wv     = threadIdx.x >> 6;
    const int h      = lane64 >> 5;        // half (atom within wave)
    const int s      = lane64 & 31;
    const int ea     = 31 - s;             // edge index (reversed: suffix -> DPP prefix)
    const int i      = blockIdx.x * 8 + wv * 2 + h;
    const bool valid = (i < N);
    const int isafe  = valid ? i : 0;
    AtomLds& L = lds[wv * 2 + h];

    const float* wm = ws + 80;

    // ---- atom-level quantities (broadcast within each half) ----
    const int   spi = species[isafe];
    const float mgx = mag[3*isafe+0], mgy = mag[3*isafe+1], mgz = mag[3*isafe+2];
    const float u_i = mgx*mgx + mgy*mgy + mgz*mgz;
    const float mi_inv = (u_i > 1e-16f) ? __builtin_amdgcn_rsqf(u_i) : 0.0f;
    const float mix = mgx*mi_inv, miy = mgy*mi_inv, miz = mgz*mi_inv;
    const float pix = pos[3*isafe+0], piy = pos[3*isafe+1], piz = pos[3*isafe+2];

    // ---- phase 1: per-edge (this lane owns edge ea of atom i) ----
    float phi[8];
    float rx = 0.0f, ry = 0.0f, rz = 0.0f;
    #pragma unroll
    for (int n = 0; n < 8; ++n) phi[n] = 0.0f;

    if (ea < K) {
        const int e = isafe * K + ea;
        const int j = eidx[E + e];
        rx = pos[3*j+0] - pix + shifts[3*e+0];
        ry = pos[3*j+1] - piy + shifts[3*e+1];
        rz = pos[3*j+2] - piz + shifts[3*e+2];
        const float d2 = rx*rx + ry*ry + rz*rz;
        const float dist = __builtin_amdgcn_sqrtf(d2);
        const float fc = (dist < RCUT)
            ? (0.5f * __builtin_amdgcn_cosf(dist * 0.1f) + 0.5f)   // cos(pi d/5), revolutions
            : 0.0f;
        const float xr = dist * (1.0f/RCUT);
        const float x  = 2.0f * xr * xr - 1.0f;
        v2f f2[4];
        {
            float fp[8];
            float Tm2 = 1.0f, Tm1 = x;
            fp[0] = 0.5f * (Tm2 + 1.0f) * fc;
            fp[1] = 0.5f * (Tm1 + 1.0f) * fc;
            #pragma unroll
            for (int k = 2; k < 8; ++k) {
                const float T = 2.0f * x * Tm1 - Tm2;
                Tm2 = Tm1; Tm1 = T;
                fp[k] = 0.5f * (T + 1.0f) * fc;
            }
            f2[0] = (v2f){fp[0], fp[1]};
            f2[1] = (v2f){fp[2], fp[3]};
            f2[2] = (v2f){fp[4], fp[5]};
            f2[3] = (v2f){fp[6], fp[7]};
        }
        const int spj = species[j];
        const float4* rb4 = (const float4*)(rb + (spi * NSPEC + spj) * 64);
        #pragma unroll
        for (int n = 0; n < 8; ++n) {
            const float4 r0 = rb4[n*2+0];
            const float4 r1 = rb4[n*2+1];
            v2f a2 = f2[0] * (v2f){r0.x, r0.y};
            a2 += f2[1] * (v2f){r0.z, r0.w};
            a2 += f2[2] * (v2f){r1.x, r1.y};
            a2 += f2[3] * (v2f){r1.z, r1.w};
            const float ph = a2.x + a2.y;
            phi[n] = ph;
            L.phiT[n*PADR + ea] = ph;
        }
        const float dinv = (dist > 1e-8f) ? __builtin_amdgcn_rcpf(dist) : 1e8f;
        L.rhx[ea] = rx * dinv;
        L.rhy[ea] = ry * dinv;
        L.rhz[ea] = rz * dinv;
        const float mjx = mag[3*j+0], mjy = mag[3*j+1], mjz = mag[3*j+2];
        const float uj = mjx*mjx + mjy*mjy + mjz*mjz;
        const float mjinv = (uj > 1e-16f) ? __builtin_amdgcn_rsqf(uj) : 0.0f;
        L.mdx[ea] = mjx * mjinv;
        L.mdy[ea] = mjy * mjinv;
        L.mdz[ea] = mjz * mjinv;
        L.uj[ea] = uj;
    } else {
        #pragma unroll
        for (int n = 0; n < 8; ++n) L.phiT[n*PADR + ea] = 0.0f;
        L.rhx[ea] = 0.0f; L.rhy[ea] = 0.0f; L.rhz[ea] = 0.0f;
        L.mdx[ea] = 0.0f; L.mdy[ea] = 0.0f; L.mdz[ea] = 0.0f;
        L.uj[ea] = 0.0f;
    }
    lds_fence();   // phase-1 stores -> phase-2 reads (intra-wave)

    float p = 0.0f;   // fused weighted-descriptor accumulator

    // ---- phase 2: segment sums (packed-FP32 accumulators) + epilogue in k4==0 lanes ----
    {
        const int k4 = s >> 3;
        const int n  = s & 7;
        const float4* phR = (const float4*)&L.phiT[n*PADR + k4*8];
        const float4* hxR = (const float4*)&L.rhx[k4*8];
        const float4* hyR = (const float4*)&L.rhy[k4*8];
        const float4* hzR = (const float4*)&L.rhz[k4*8];
        const float4* dxR = (const float4*)&L.mdx[k4*8];
        const float4* dyR = (const float4*)&L.mdy[k4*8];
        const float4* dzR = (const float4*)&L.mdz[k4*8];
        const float4* ujR = (const float4*)&L.uj[k4*8];

        float s_dr = 0.0f, sP2 = 0.0f, s_nb = 0.0f, sM2 = 0.0f, sW0 = 0.0f;
        v2f A1 = {0,0};   // (P0,P1)
        v2f A3 = {0,0};   // (Qxx', Qxy)   (no -1/3; corrected at end via a_dr/3)
        v2f A4 = {0,0};   // (Qxz, Qyy')
        v2f A5 = {0,0};   // (Qyz, Qzz')
        v2f A6 = {0,0};   // (M0, M1)
        v2f A8 = {0,0};   // (W1, W2)

        auto acc = [&](float ph, float hx, float hy, float hz,
                       float dx, float dy, float dz, float uj) {
            const float phu = ph * uj;
            s_dr += ph;
            s_nb += phu;
            sP2 += ph * hz;
            sM2 += ph * dz;
            sW0 += phu * dx;
            A1 += ph * (v2f){hx, hy};
            A3 += ph * ((v2f){hx, hx} * (v2f){hx, hy});
            A4 += ph * ((v2f){hx, hy} * (v2f){hz, hy});
            A5 += ph * ((v2f){hy, hz} * (v2f){hz, hz});
            A6 += ph * (v2f){dx, dy};
            A8 += phu * (v2f){dy, dz};
        };
        #pragma unroll
        for (int q = 0; q < 2; ++q) {
            const float4 ph4 = phR[q], hx4 = hxR[q], hy4 = hyR[q], hz4 = hzR[q];
            const float4 dx4 = dxR[q], dy4 = dyR[q], dz4 = dzR[q], uj4 = ujR[q];
            acc(ph4.x, hx4.x, hy4.x, hz4.x, dx4.x, dy4.x, dz4.x, uj4.x);
            acc(ph4.y, hx4.y, hy4.y, hz4.y, dx4.y, dy4.y, dz4.y, uj4.y);
            acc(ph4.z, hx4.z, hy4.z, hz4.z, dx4.z, dy4.z, dz4.z, uj4.z);
            acc(ph4.w, hx4.w, hy4.w, hz4.w, dx4.w, dy4.w, dz4.w, uj4.w);
        }
        s_dr = red_k4(s_dr); sP2 = red_k4(sP2); s_nb = red_k4(s_nb);
        sM2 = red_k4(sM2);   sW0 = red_k4(sW0);
        A1 = red_k4_v2(A1); A3 = red_k4_v2(A3); A4 = red_k4_v2(A4);
        A5 = red_k4_v2(A5); A6 = red_k4_v2(A6); A8 = red_k4_v2(A8);

        if (k4 == 0) {
            const float dr3 = s_dr * (1.0f/3.0f);
            const float aP0 = A1.x, aP1 = A1.y, aP2 = sP2;
            const float aQ0 = A3.x - dr3, aQ1 = A3.y, aQ2 = A4.x;
            const float aQ3 = A4.y - dr3, aQ4 = A5.x, aQ5 = A5.y - dr3;
            const float aM0 = A6.x, aM1 = A6.y, aM2 = sM2;
            const float aW0 = sW0, aW1 = A8.x, aW2 = A8.y;

            ((float4*)L.P4)[n]     = make_float4(aP0, aP1, aP2, 0.0f);
            ((float4*)L.Q8)[2*n]   = make_float4(aQ0, aQ1, aQ2, aQ3);
            ((float4*)L.Q8)[2*n+1] = make_float4(aQ4, aQ5, 0.0f, 0.0f);
            ((float4*)L.M4)[n]     = make_float4(aM0, aM1, aM2, 0.0f);
            const float mq0 = aQ0*mix + aQ1*miy + aQ2*miz;
            const float mq1 = aQ1*mix + aQ3*miy + aQ4*miz;
            const float mq2 = aQ2*mix + aQ4*miy + aQ5*miz;
            ((float4*)L.mQ4)[n]    = make_float4(mq0, mq1, mq2, 0.0f);
            ((float4*)L.wv4)[n]    = make_float4(miy*aM2 - miz*aM1,
                                                 miz*aM0 - mix*aM2,
                                                 mix*aM1 - miy*aM0, 0.0f);
            const float diso = mix*aM0 + miy*aM1 + miz*aM2;
            const float dsia = mq0*mix + mq1*miy + mq2*miz;
            const float dnex = mix*aW0 + miy*aW1 + miz*aW2;
            p += s_dr * ws[n] + s_nb * wm[227 + n]
               + diso * wm[3 + n]  + dsia * wm[11 + n]  + dnex * wm[235 + n]
               + u_i * (diso * wm[147 + n] + dsia * wm[155 + n] + dnex * wm[243 + n]);
        }
        if (s == 8) {                   // d_amp
            const float u2 = u_i * u_i;
            p += u_i * wm[0] + u2 * wm[1] + u2 * u_i * wm[2];
        }
        if (s < EMBEDD)                 // embedding term
            p += semb[spi * EMBEDD + s] * ws[332 + s];
    }
    lds_fence();   // epilogue stores -> phase-3 / 4b reads

    // ---- phase 3: DMI, fused weights, packed B (pairs over m) ----
    {
        const v2f* cw1 = (const v2f*)(ws + 400);   // [n][m-pair]
        const v2f* cw2 = (const v2f*)(ws + 464);
        v2f B1[4] = {{0,0},{0,0},{0,0},{0,0}};
        v2f B2[4] = {{0,0},{0,0},{0,0},{0,0}};
        #pragma unroll
        for (int n = 0; n < 8; ++n) {
            #pragma unroll
            for (int jj = 0; jj < 4; ++jj) {
                B1[jj] += phi[n] * cw1[n*4 + jj];
                B2[jj] += phi[n] * cw2[n*4 + jj];
            }
        }
        v2f Bp[4];
        #pragma unroll
        for (int jj = 0; jj < 4; ++jj) Bp[jj] = B1[jj] + u_i * B2[jj];

        float cdmi = 0.0f;
        #pragma unroll
        for (int m = 0; m < 8; ++m) {
            const float4 wvm = ((const float4*)L.wv4)[m];
            const float vx = phi[m] * rx;
            const float vy = phi[m] * ry;
            const float vz = phi[m] * rz;
            const float Sx = prefix32(vx) - vx;   // exclusive suffix (b > ea)
            const float Sy = prefix32(vy) - vy;
            const float Sz = prefix32(vz) - vz;
            const float cx = ry*Sz - rz*Sy;
            const float cy = rz*Sx - rx*Sz;
            const float cz = rx*Sy - ry*Sx;
            const float Bm = (m & 1) ? Bp[m >> 1].y : Bp[m >> 1].x;
            cdmi = fmaf(Bm, cx*wvm.x + cy*wvm.y + cz*wvm.z, cdmi);
        }
        p += cdmi;
    }

    // ---- phase 4b: d_sae + PP/QQ upper triangles ----
    {
        #pragma unroll
        for (int t2 = 0; t2 < 2; ++t2) {
            const int idx = s + t2*32;
            const int m4 = idx >> 3, n4 = idx & 7;
            const float4 mQm = ((const float4*)L.mQ4)[m4];
            const float4 Mn  = ((const float4*)L.M4)[n4];
            p += (mQm.x*Mn.x + mQm.y*Mn.y + mQm.z*Mn.z) * wm[19 + idx];
        }
        #pragma unroll
        for (int t2 = 0; t2 < 2; ++t2) {
            const int idx = s + t2*32;
            if (idx < 36) {
                const int a = TUN[idx], b = TUM[idx];
                const float4 Pa = ((const float4*)L.P4)[a];
                const float4 Pb = ((const float4*)L.P4)[b];
                const float pp = Pa.x*Pb.x + Pa.y*Pb.y + Pa.z*Pb.z;
                const float4 Qa0 = ((const float4*)L.Q8)[2*a], Qa1 = ((const float4*)L.Q8)[2*a+1];
                const float4 Qb0 = ((const float4*)L.Q8)[2*b], Qb1 = ((const float4*)L.Q8)[2*b+1];
                const float qq = Qa0.x*Qb0.x + Qa0.w*Qb0.w + Qa1.y*Qb1.y
                       + 2.0f*(Qa0.y*Qb0.y + Qa0.z*Qb0.z + Qa1.x*Qb1.x);
                p += pp * ws[8 + idx] + qq * ws[44 + idx];
            }
        }
    }

    // ---- final: reduce p within each 32-half, lane 0 writes ----
    p = red32(p);
    if (s == 0 && valid)
        out[i] = p + ws[331] + aes[spi];
}

extern "C" void kernel_launch(void* const* d_in, const int* in_sizes, int n_in,
                              void* d_out, int out_size, void* d_ws, size_t ws_size,
                              hipStream_t stream) {
    const float* pos     = (const float*)d_in[0];
    const int*   spc     = (const int*)  d_in[1];
    const float* mg      = (const float*)d_in[2];
    const int*   eidx    = (const int*)  d_in[3];
    const float* shf     = (const float*)d_in[4];
    const float* rb      = (const float*)d_in[5];
    const float* semb    = (const float*)d_in[6];
    const float* sshift  = (const float*)d_in[7];
    const float* sscale  = (const float*)d_in[8];
    const float* mshift  = (const float*)d_in[9];
    const float* mscale  = (const float*)d_in[10];
    const float* aes     = (const float*)d_in[11];
    const float* wstruct = (const float*)d_in[12];
    const float* bstruct = (const float*)d_in[13];
    const float* wmag    = (const float*)d_in[14];
    const float* bmag    = (const float*)d_in[15];
    float* out = (float*)d_out;
    float* ws  = (float*)d_ws;

    const int N = in_sizes[1];
    const int E = in_sizes[3] / 2;
    const int K = E / N;

    hipLaunchKernelGGL(magpot_setup, dim3(1), dim3(256), 0, stream,
                       sshift, sscale, mshift, mscale, wstruct, bstruct, wmag, bmag, ws);
    hipLaunchKernelGGL(magpot_main, dim3((N + 7) / 8), dim3(256), 0, stream,
                       pos, spc, mg, eidx, shf, rb, semb, aes, ws, out, N, E, K);
}